// Round 11
// baseline (36.419 us; speedup 1.0000x reference)
//
#include <hip/hip_runtime.h>
#include <hip/hip_bf16.h>
#include <math.h>

// AFM: B=4096, F=24, D=64, A=64, P=F*(F-1)/2=276
#define NF 24
#define ND 64
#define NA 64
#define NP 276
#define NPAD 288
#define NTILE 18
#define NT 256      // 4 waves per block; wave w handles batch blockIdx*4+w
#define BPB 4

typedef short bf16x8 __attribute__((ext_vector_type(8)));
typedef float f32x4  __attribute__((ext_vector_type(4)));

__device__ __forceinline__ short f2bf(float f) {
    __hip_bfloat16 h = __float2bfloat16(f);      // RNE
    union { __hip_bfloat16 h; unsigned short u; } cv;
    cv.h = h;
    return (short)cv.u;
}
__device__ __forceinline__ float bf2f(short s) {
    union { unsigned u; float f; } cv;
    cv.u = ((unsigned)(unsigned short)s) << 16;
    return cv.f;
}

// ---- DPP helpers (VALU-pipe cross-lane, no LDS); ctrl must be constexpr ----
template <int CTRL, int RMASK>
__device__ __forceinline__ float dpp_add_step(float v) {
    int moved = __builtin_amdgcn_update_dpp(0, __float_as_int(v), CTRL, RMASK, 0xf, true);
    return v + __int_as_float(moved);
}
template <int CTRL, int RMASK>
__device__ __forceinline__ float dpp_max_step(float v) {
    int moved = __builtin_amdgcn_update_dpp(__float_as_int(v), __float_as_int(v), CTRL, RMASK, 0xf, false);
    return fmaxf(v, __int_as_float(moved));
}
// sum of each 16-lane row, result valid at lane 0 of the row (row_shl)
__device__ __forceinline__ float row16_sum0(float v) {
    v = dpp_add_step<0x101, 0xf>(v);   // row_shl 1
    v = dpp_add_step<0x102, 0xf>(v);   // row_shl 2
    v = dpp_add_step<0x104, 0xf>(v);   // row_shl 4
    v = dpp_add_step<0x108, 0xf>(v);   // row_shl 8
    return v;
}
__device__ __forceinline__ float wave_sum(float v) {
    v = dpp_add_step<0x111, 0xf>(v);   // row_shr 1
    v = dpp_add_step<0x112, 0xf>(v);   // row_shr 2
    v = dpp_add_step<0x114, 0xf>(v);   // row_shr 4
    v = dpp_add_step<0x118, 0xf>(v);   // row_shr 8
    v = dpp_add_step<0x142, 0xa>(v);   // row_bcast:15 -> rows 1,3
    v = dpp_add_step<0x143, 0xc>(v);   // row_bcast:31 -> rows 2,3
    return __int_as_float(__builtin_amdgcn_readlane(__float_as_int(v), 63));
}
__device__ __forceinline__ float wave_max(float v) {
    v = dpp_max_step<0x111, 0xf>(v);
    v = dpp_max_step<0x112, 0xf>(v);
    v = dpp_max_step<0x114, 0xf>(v);
    v = dpp_max_step<0x118, 0xf>(v);
    v = dpp_max_step<0x142, 0xa>(v);
    v = dpp_max_step<0x143, 0xc>(v);
    return __int_as_float(__builtin_amdgcn_readlane(__float_as_int(v), 63));
}

// ws layout (shorts):
//   [0, 4096)    waF:  [lane 64][chunk 8 = nt*2+kh][8 bf16]
//   [4096, 5120) wfcF: [lane 64][kh 2][8 bf16]  (col0=hi, col1=lo)
//   [5120, 5696) rc:   288 ints, packed (r<<16)|c, pad pairs = (0,0)
__global__ __launch_bounds__(64) void afm_prep_kernel(
    const float* __restrict__ Wa,
    const float* __restrict__ Wfc,
    short* __restrict__ ws)
{
    const int l  = (int)threadIdx.x;
    const int lg = l >> 4, li = l & 15;
    short* waF  = ws;
    short* wfcF = ws + 64 * 64;
    int*   rc   = (int*)(ws + 64 * 64 + 64 * 16);
    #pragma unroll
    for (int nt = 0; nt < 4; ++nt)
        #pragma unroll
        for (int kh = 0; kh < 2; ++kh)
            #pragma unroll
            for (int i = 0; i < 8; ++i) {
                int d = kh * 32 + lg * 8 + i;
                waF[l * 64 + (nt * 2 + kh) * 8 + i] = f2bf(Wa[d * NA + nt * 16 + li]);
            }
    #pragma unroll
    for (int kh = 0; kh < 2; ++kh)
        #pragma unroll
        for (int i = 0; i < 8; ++i) {
            int d = kh * 32 + lg * 8 + i;
            float w = Wfc[d];
            short hi = f2bf(w);
            short lo = f2bf(w - bf2f(hi));
            wfcF[l * 16 + kh * 8 + i] = (li == 0) ? hi : ((li == 1) ? lo : (short)0);
        }
    for (int p0 = l; p0 < NPAD; p0 += 64) {
        int r = 0, c = 0;
        if (p0 < NP) {
            int rem = p0;
            while (rem >= NF - 1 - r) { rem -= NF - 1 - r; ++r; }
            c = r + 1 + rem;
        }
        rc[p0] = (r << 16) | c;
    }
}

__global__ __launch_bounds__(NT) void afm_mfma_kernel(
    const float* __restrict__ x,
    const float* __restrict__ ba,
    const float* __restrict__ Wp,
    const float* __restrict__ bfc,
    const short* __restrict__ ws,
    float* __restrict__ out)
{
    const int tid  = (int)threadIdx.x;
    const int lane = tid & 63;
    const int wid  = tid >> 6;
    const int b    = blockIdx.x * BPB + wid;   // this wave's batch
    const int lg   = lane >> 4;
    const int li   = lane & 15;

    __shared__ float  xs[BPB][NF][68];   // per-wave x tile (float4-aligned rows)
    __shared__ float2 lv[BPB][NPAD];     // per-wave {logit, v}

    // ---- stage x[b] into this wave's LDS region (no cross-wave deps) ----
    const float4* xb4 = (const float4*)(x + (size_t)b * (NF * ND));
    #pragma unroll
    for (int k = 0; k < 6; ++k) {
        int i = lane + k * 64;           // 0..383
        float4 v = xb4[i];
        *(float4*)&xs[wid][i >> 4][(i & 15) * 4] = v;
    }

    // ---- fragments from ws: 10 vector loads, no cvt ----
    const bf16x8* waF  = (const bf16x8*)ws;              // [64][8]
    const bf16x8* wfcF = (const bf16x8*)(ws + 64 * 64);  // [64][2]
    const int*    rcg  = (const int*)(ws + 64 * 64 + 64 * 16);
    bf16x8 WaF[4][2];
    #pragma unroll
    for (int nt = 0; nt < 4; ++nt)
        #pragma unroll
        for (int kh = 0; kh < 2; ++kh)
            WaF[nt][kh] = waF[lane * 8 + nt * 2 + kh];
    bf16x8 WfcF[2] = { wfcF[lane * 2 + 0], wfcF[lane * 2 + 1] };

    float ba_reg[4], wp_reg[4];
    #pragma unroll
    for (int nt = 0; nt < 4; ++nt) {
        ba_reg[nt] = ba[nt * 16 + li];
        wp_reg[nt] = Wp[nt * 16 + li];
    }

    // in-wave ordering of staging writes vs tile reads (compiler also tracks)
    asm volatile("s_waitcnt lgkmcnt(0)" ::: "memory");

    // ---- tile loop, 2 tiles interleaved: two independent dep chains ----
    #pragma unroll 1
    for (int t = 0; t < NTILE; t += 2) {
        int pr0 = rcg[t * 16 + li];
        int pr1 = rcg[t * 16 + 16 + li];
        int rI0 = pr0 >> 16, cI0 = pr0 & 0xffff;
        int rI1 = pr1 >> 16, cI1 = pr1 & 0xffff;

        bf16x8 Ah0[2], Ah1[2];
        #pragma unroll
        for (int kh = 0; kh < 2; ++kh) {
            int d0 = kh * 32 + lg * 8;
            const float4* pr0p = reinterpret_cast<const float4*>(&xs[wid][rI0][d0]);
            const float4* pc0p = reinterpret_cast<const float4*>(&xs[wid][cI0][d0]);
            const float4* pr1p = reinterpret_cast<const float4*>(&xs[wid][rI1][d0]);
            const float4* pc1p = reinterpret_cast<const float4*>(&xs[wid][cI1][d0]);
            float4 a0 = pr0p[0], a1 = pr0p[1], b0 = pc0p[0], b1 = pc0p[1];
            float4 e0 = pr1p[0], e1 = pr1p[1], g0 = pc1p[0], g1 = pc1p[1];
            Ah0[kh][0] = f2bf(a0.x * b0.x);  Ah0[kh][1] = f2bf(a0.y * b0.y);
            Ah0[kh][2] = f2bf(a0.z * b0.z);  Ah0[kh][3] = f2bf(a0.w * b0.w);
            Ah0[kh][4] = f2bf(a1.x * b1.x);  Ah0[kh][5] = f2bf(a1.y * b1.y);
            Ah0[kh][6] = f2bf(a1.z * b1.z);  Ah0[kh][7] = f2bf(a1.w * b1.w);
            Ah1[kh][0] = f2bf(e0.x * g0.x);  Ah1[kh][1] = f2bf(e0.y * g0.y);
            Ah1[kh][2] = f2bf(e0.z * g0.z);  Ah1[kh][3] = f2bf(e0.w * g0.w);
            Ah1[kh][4] = f2bf(e1.x * g1.x);  Ah1[kh][5] = f2bf(e1.y * g1.y);
            Ah1[kh][6] = f2bf(e1.z * g1.z);  Ah1[kh][7] = f2bf(e1.w * g1.w);
        }

        f32x4 acc0[4], acc1[4];
        #pragma unroll
        for (int nt = 0; nt < 4; ++nt) {
            acc0[nt] = (f32x4){0.f, 0.f, 0.f, 0.f};
            acc0[nt] = __builtin_amdgcn_mfma_f32_16x16x32_bf16(Ah0[0], WaF[nt][0], acc0[nt], 0, 0, 0);
            acc0[nt] = __builtin_amdgcn_mfma_f32_16x16x32_bf16(Ah0[1], WaF[nt][1], acc0[nt], 0, 0, 0);
            acc1[nt] = (f32x4){0.f, 0.f, 0.f, 0.f};
            acc1[nt] = __builtin_amdgcn_mfma_f32_16x16x32_bf16(Ah1[0], WaF[nt][0], acc1[nt], 0, 0, 0);
            acc1[nt] = __builtin_amdgcn_mfma_f32_16x16x32_bf16(Ah1[1], WaF[nt][1], acc1[nt], 0, 0, 0);
        }
        f32x4 accv0 = (f32x4){0.f, 0.f, 0.f, 0.f};
        f32x4 accv1 = (f32x4){0.f, 0.f, 0.f, 0.f};
        accv0 = __builtin_amdgcn_mfma_f32_16x16x32_bf16(Ah0[0], WfcF[0], accv0, 0, 0, 0);
        accv0 = __builtin_amdgcn_mfma_f32_16x16x32_bf16(Ah0[1], WfcF[1], accv0, 0, 0, 0);
        accv1 = __builtin_amdgcn_mfma_f32_16x16x32_bf16(Ah1[0], WfcF[0], accv1, 0, 0, 0);
        accv1 = __builtin_amdgcn_mfma_f32_16x16x32_bf16(Ah1[1], WfcF[1], accv1, 0, 0, 0);

        // epilogues: DPP row reduce (VALU pipe), write {logit, v} at li==0
        #pragma unroll
        for (int j = 0; j < 4; ++j) {
            float l0 = 0.f, l1 = 0.f;
            #pragma unroll
            for (int nt = 0; nt < 4; ++nt) {
                float h0 = fmaxf(acc0[nt][j] + ba_reg[nt], 0.f);
                l0 = fmaf(h0, wp_reg[nt], l0);
                float h1 = fmaxf(acc1[nt][j] + ba_reg[nt], 0.f);
                l1 = fmaf(h1, wp_reg[nt], l1);
            }
            l0 = row16_sum0(l0);
            l1 = row16_sum0(l1);
            int mv0 = __builtin_amdgcn_update_dpp(0, __float_as_int(accv0[j]), 0xB1, 0xf, 0xf, true);
            int mv1 = __builtin_amdgcn_update_dpp(0, __float_as_int(accv1[j]), 0xB1, 0xf, 0xf, true);
            float vv0 = accv0[j] + __int_as_float(mv0);
            float vv1 = accv1[j] + __int_as_float(mv1);
            int row = t * 16 + lg * 4 + j;
            if (li == 0) {
                lv[wid][row]      = make_float2(l0, vv0);
                lv[wid][row + 16] = make_float2(l1, vv1);
            }
        }
    }

    asm volatile("s_waitcnt lgkmcnt(0)" ::: "memory");

    // ---- per-wave softmax fused with output ----
    float2 myv[5];
    float m = -INFINITY;
    #pragma unroll
    for (int k = 0; k < 5; ++k) {
        int p = lane + k * 64;
        if (p < NP) { myv[k] = lv[wid][p]; m = fmaxf(m, myv[k].x); }
        else        { myv[k] = make_float2(-INFINITY, 0.f); }
    }
    m = wave_max(m);

    float se = 0.f, sev = 0.f;
    #pragma unroll
    for (int k = 0; k < 5; ++k) {
        int p = lane + k * 64;
        if (p < NP) {
            float e = __expf(myv[k].x - m);
            se += e;
            sev = fmaf(e, myv[k].y, sev);
        }
    }
    se  = wave_sum(se);
    sev = wave_sum(sev);
    if (lane == 0)
        out[b] = sev / se + bfc[0];
}

extern "C" void kernel_launch(void* const* d_in, const int* in_sizes, int n_in,
                              void* d_out, int out_size, void* d_ws, size_t ws_size,
                              hipStream_t stream) {
    const float* x   = (const float*)d_in[0];
    const float* Wa  = (const float*)d_in[1];
    const float* ba  = (const float*)d_in[2];
    const float* Wp  = (const float*)d_in[3];
    // d_in[4] = bp  (unused: softmax shift-invariant)
    const float* Wfc = (const float*)d_in[5];
    const float* bfc = (const float*)d_in[6];
    float* out = (float*)d_out;
    short* ws  = (short*)d_ws;

    const int B = in_sizes[0] / (NF * ND);
    hipLaunchKernelGGL(afm_prep_kernel, dim3(1), dim3(64), 0, stream, Wa, Wfc, ws);
    hipLaunchKernelGGL(afm_mfma_kernel, dim3(B / BPB), dim3(NT), 0, stream,
                       x, ba, Wp, bfc, ws, out);
}